// Round 1
// baseline (2960.212 us; speedup 1.0000x reference)
//
#include <hip/hip_runtime.h>
#include <hip/hip_bf16.h>

// ---------------------------------------------------------------------------
// 3-layer BERT-ish encoder forward on MI355X (gfx950).
// All matmuls: one bf16-MFMA GEMM kernel computing C = alpha*A*B^T + bias,
// fp32 in/out, bf16 conversion during LDS staging, fp32 accumulation.
//   A: [M,K] row-major, B: [N,K] row-major (i.e. weights as stored, B^T form)
// Batched via blockIdx.z decomposed as (b = z>>3, h = z&7) with 6 strides.
// Attention V is pre-transposed per (b,h) into Vt[d][k] so A*V is also B^T form.
// ---------------------------------------------------------------------------

typedef __bf16 bf16_t;
typedef __bf16 bf16x4 __attribute__((ext_vector_type(4)));
typedef __bf16 bf16x8 __attribute__((ext_vector_type(8)));
typedef float  f32x4  __attribute__((ext_vector_type(4)));

// ---------------------------------------------------------------------------
// Embedding: x[t] = emb[ids[t]] + pos_emb[t % 512]
// ---------------------------------------------------------------------------
__global__ __launch_bounds__(256) void embed_kernel(
    const int* __restrict__ ids, const float* __restrict__ emb,
    const float* __restrict__ pos, float* __restrict__ x)
{
    int g = blockIdx.x * 256 + threadIdx.x;        // 0 .. 16384*128-1 (float4 units)
    int token = g >> 7, c4 = g & 127;
    int id = ids[token];
    float4 e = ((const float4*)emb)[(long long)id * 128 + c4];
    float4 p = ((const float4*)pos)[(long long)(token & 511) * 128 + c4];
    e.x += p.x; e.y += p.y; e.z += p.z; e.w += p.w;
    ((float4*)x)[g] = e;
}

// ---------------------------------------------------------------------------
// GEMM: C = alpha * A (MxK) * B^T (B is [N,K]) + bias, optional exact GELU.
// 64x64 tile, BK=64, 256 threads = 4 waves, wave w -> rows [w*16, w*16+16).
// mfma_f32_16x16x32_bf16; A/B frag: [m|n = lane&15][k = (lane>>4)*8 + j]
// C/D frag: col = lane&15, row = (lane>>4)*4 + reg   (HW-verified mapping)
// ---------------------------------------------------------------------------
template<int GELU>
__global__ __launch_bounds__(256) void gemm_bt(
    const float* __restrict__ A, const float* __restrict__ B,
    float* __restrict__ C, const float* __restrict__ bias,
    int lda, int ldb, int ldc, int K,
    long long sAb, long long sAh, long long sBb, long long sBh,
    long long sCb, long long sCh, float alpha)
{
    __shared__ __align__(16) bf16_t As[64 * 64];
    __shared__ __align__(16) bf16_t Bs[64 * 64];

    int m0 = blockIdx.x * 64, n0 = blockIdx.y * 64;
    int z = blockIdx.z, zb = z >> 3, zh = z & 7;
    A += (long long)zb * sAb + (long long)zh * sAh + (long long)m0 * lda;
    B += (long long)zb * sBb + (long long)zh * sBh + (long long)n0 * ldb;
    C += (long long)zb * sCb + (long long)zh * sCh;

    int tid = threadIdx.x;
    int wave = tid >> 6, lane = tid & 63, q = lane >> 4, r = lane & 15;

    f32x4 acc[4];
#pragma unroll
    for (int i = 0; i < 4; i++) acc[i] = (f32x4){0.f, 0.f, 0.f, 0.f};

    for (int k0 = 0; k0 < K; k0 += 64) {
#pragma unroll
        for (int ii = 0; ii < 4; ii++) {
            int f = tid + 256 * ii;              // 1024 float4s per operand tile
            int rowi = f >> 4, c4 = (f & 15) << 2;
            float4 av = *(const float4*)(A + (long long)rowi * lda + k0 + c4);
            float4 bv = *(const float4*)(B + (long long)rowi * ldb + k0 + c4);
            bf16x4 ap, bp;
            ap[0] = (bf16_t)av.x; ap[1] = (bf16_t)av.y; ap[2] = (bf16_t)av.z; ap[3] = (bf16_t)av.w;
            bp[0] = (bf16_t)bv.x; bp[1] = (bf16_t)bv.y; bp[2] = (bf16_t)bv.z; bp[3] = (bf16_t)bv.w;
            *(bf16x4*)(As + rowi * 64 + c4) = ap;
            *(bf16x4*)(Bs + rowi * 64 + c4) = bp;
        }
        __syncthreads();
#pragma unroll
        for (int kk = 0; kk < 64; kk += 32) {
            bf16x8 af = *(const bf16x8*)(As + (wave * 16 + r) * 64 + kk + q * 8);
#pragma unroll
            for (int fn = 0; fn < 4; fn++) {
                bf16x8 bfv = *(const bf16x8*)(Bs + (fn * 16 + r) * 64 + kk + q * 8);
                acc[fn] = __builtin_amdgcn_mfma_f32_16x16x32_bf16(af, bfv, acc[fn], 0, 0, 0);
            }
        }
        __syncthreads();
    }

#pragma unroll
    for (int fn = 0; fn < 4; fn++) {
        int col = n0 + fn * 16 + r;
        float bv = bias ? bias[col] : 0.f;
#pragma unroll
        for (int i = 0; i < 4; i++) {
            int rowi = m0 + wave * 16 + q * 4 + i;
            float v = acc[fn][i] * alpha + bv;
            if (GELU) v = 0.5f * v * (1.f + erff(v * 0.70710678118654752f));
            C[(long long)rowi * ldc + col] = v;
        }
    }
}

// ---------------------------------------------------------------------------
// Per-(b,h) transpose of V out of qkv: Vt[z][d][k] = qkv[b*512+k][1024+h*64+d]
// ---------------------------------------------------------------------------
__global__ __launch_bounds__(256) void transpose_v(
    const float* __restrict__ qkv, float* __restrict__ Vt)
{
    int z = blockIdx.x, b = z >> 3, h = z & 7;
    int k0 = blockIdx.y * 64;
    __shared__ float t[64][65];
    const float* src = qkv + (long long)(b * 512 + k0) * 1536 + 1024 + h * 64;
    int tid = threadIdx.x;
#pragma unroll
    for (int ii = 0; ii < 16; ii++) {
        int idx = tid + 256 * ii;
        int i = idx >> 6, j = idx & 63;          // i: k-row, j: d-col (coalesced)
        t[i][j] = src[(long long)i * 1536 + j];
    }
    __syncthreads();
    float* dst = Vt + (long long)z * 64 * 512 + k0;
#pragma unroll
    for (int ii = 0; ii < 16; ii++) {
        int idx = tid + 256 * ii;
        int d = idx >> 6, kk = idx & 63;         // write coalesced along k
        dst[(long long)d * 512 + kk] = t[kk][d];
    }
}

// ---------------------------------------------------------------------------
// In-place masked softmax over rows of 512. One wave per row.
// ---------------------------------------------------------------------------
__global__ __launch_bounds__(256) void softmax_kernel(
    float* __restrict__ a, const int* __restrict__ amask)
{
    long long row = (long long)blockIdx.x * 4 + (threadIdx.x >> 6);
    int lane = threadIdx.x & 63;
    int b = (int)(row >> 12);                    // row = (b*8+h)*512 + q
    float* p = a + row * 512;
    const int* mrow = amask + b * 512;

    float v[8];
    float mx = -3.0e38f;
#pragma unroll
    for (int i = 0; i < 2; i++) {
        float4 t = ((const float4*)p)[lane + 64 * i];
        int k0 = (lane + 64 * i) * 4;
        float tv[4] = {t.x, t.y, t.z, t.w};
#pragma unroll
        for (int c = 0; c < 4; c++) {
            float s = (mrow[k0 + c] == 0) ? -__builtin_inff() : tv[c];
            v[i * 4 + c] = s;
            mx = fmaxf(mx, s);
        }
    }
#pragma unroll
    for (int o = 32; o; o >>= 1) mx = fmaxf(mx, __shfl_xor(mx, o));
    float sum = 0.f;
#pragma unroll
    for (int j = 0; j < 8; j++) { v[j] = __expf(v[j] - mx); sum += v[j]; }
#pragma unroll
    for (int o = 32; o; o >>= 1) sum += __shfl_xor(sum, o);
    float inv = 1.f / sum;
#pragma unroll
    for (int i = 0; i < 2; i++) {
        float4 t;
        t.x = v[i * 4 + 0] * inv; t.y = v[i * 4 + 1] * inv;
        t.z = v[i * 4 + 2] * inv; t.w = v[i * 4 + 3] * inv;
        ((float4*)p)[lane + 64 * i] = t;
    }
}

// ---------------------------------------------------------------------------
// x = LayerNorm(x + rsd) * g + b, row = token, E=512. One wave per row.
// ---------------------------------------------------------------------------
__global__ __launch_bounds__(256) void add_ln(
    float* __restrict__ x, const float* __restrict__ rsd,
    const float* __restrict__ g, const float* __restrict__ bta)
{
    long long row = (long long)blockIdx.x * 4 + (threadIdx.x >> 6);
    int lane = threadIdx.x & 63;
    float4* xr = (float4*)(x + row * 512);
    const float4* rr = (const float4*)(rsd + row * 512);
    float4 s0 = xr[lane], s1 = xr[lane + 64];
    float4 r0 = rr[lane], r1 = rr[lane + 64];
    s0.x += r0.x; s0.y += r0.y; s0.z += r0.z; s0.w += r0.w;
    s1.x += r1.x; s1.y += r1.y; s1.z += r1.z; s1.w += r1.w;
    float sum = s0.x + s0.y + s0.z + s0.w + s1.x + s1.y + s1.z + s1.w;
    float sq  = s0.x*s0.x + s0.y*s0.y + s0.z*s0.z + s0.w*s0.w
              + s1.x*s1.x + s1.y*s1.y + s1.z*s1.z + s1.w*s1.w;
#pragma unroll
    for (int o = 32; o; o >>= 1) { sum += __shfl_xor(sum, o); sq += __shfl_xor(sq, o); }
    float mean = sum * (1.f / 512.f);
    float var  = sq * (1.f / 512.f) - mean * mean;
    float rstd = rsqrtf(var + 1e-5f);
    const float4* g4 = (const float4*)g;
    const float4* b4 = (const float4*)bta;
    float4 gg = g4[lane], bb = b4[lane], o0;
    o0.x = (s0.x - mean) * rstd * gg.x + bb.x;
    o0.y = (s0.y - mean) * rstd * gg.y + bb.y;
    o0.z = (s0.z - mean) * rstd * gg.z + bb.z;
    o0.w = (s0.w - mean) * rstd * gg.w + bb.w;
    xr[lane] = o0;
    gg = g4[lane + 64]; bb = b4[lane + 64];
    float4 o1;
    o1.x = (s1.x - mean) * rstd * gg.x + bb.x;
    o1.y = (s1.y - mean) * rstd * gg.y + bb.y;
    o1.z = (s1.z - mean) * rstd * gg.z + bb.z;
    o1.w = (s1.w - mean) * rstd * gg.w + bb.w;
    xr[lane + 64] = o1;
}

// ---------------------------------------------------------------------------
// logits[b][c] = dot(x[b*512], cls_w[c]) + cls_b[c].  64 blocks x 1 wave.
// ---------------------------------------------------------------------------
__global__ void cls_head(const float* __restrict__ x, const float* __restrict__ w,
                         const float* __restrict__ cb, float* __restrict__ out)
{
    int b = blockIdx.x >> 1, c = blockIdx.x & 1;
    int lane = threadIdx.x;
    const float* xr = x + (long long)b * 512 * 512;  // CLS token = b*512
    const float* wr = w + c * 512;
    float s = 0.f;
#pragma unroll
    for (int i = 0; i < 8; i++) s += xr[lane + 64 * i] * wr[lane + 64 * i];
#pragma unroll
    for (int o = 32; o; o >>= 1) s += __shfl_xor(s, o);
    if (lane == 0) out[b * 2 + c] = s + cb[c];
}

// ---------------------------------------------------------------------------
extern "C" void kernel_launch(void* const* d_in, const int* in_sizes, int n_in,
                              void* d_out, int out_size, void* d_ws, size_t ws_size,
                              hipStream_t stream)
{
    const int*   ids   = (const int*)d_in[0];
    const int*   amask = (const int*)d_in[1];
    const float* emb   = (const float*)d_in[2];
    const float* pos   = (const float*)d_in[3];
    const float* in_w  = (const float*)d_in[4];
    const float* in_b  = (const float*)d_in[5];
    const float* out_w = (const float*)d_in[6];
    const float* out_b = (const float*)d_in[7];
    const float* ln1g  = (const float*)d_in[8];
    const float* ln1b  = (const float*)d_in[9];
    const float* ln2g  = (const float*)d_in[10];
    const float* ln2b  = (const float*)d_in[11];
    const float* f1w   = (const float*)d_in[12];
    const float* f1b   = (const float*)d_in[13];
    const float* f2w   = (const float*)d_in[14];
    const float* f2b   = (const float*)d_in[15];
    const float* clsw  = (const float*)d_in[16];
    const float* clsb  = (const float*)d_in[17];

    float* outp = (float*)d_out;
    float* ws = (float*)d_ws;
    // ws layout (floats): x[8388608] | buf1[33554432] | buf2[8388608]  = 201 MB
    float* x    = ws;
    float* buf1 = ws + 8388608;
    float* qkv  = buf1;                  // [16384,1536] lives in buf1 head
    float* Vt   = buf1 + 25165824;       // [256,64,512] in buf1 tail
    float* buf2 = buf1 + 33554432;       // [16384,512]

    embed_kernel<<<8192, 256, 0, stream>>>(ids, emb, pos, x);

    for (int l = 0; l < 3; l++) {
        float* attnL = outp + 64 + (long long)l * 67108864;  // [32,8,512,512]

        // qkv = x @ Wqkv^T + b   [16384,1536]
        gemm_bt<0><<<dim3(256, 24, 1), 256, 0, stream>>>(
            x, in_w + (long long)l * 786432, qkv, in_b + l * 1536,
            512, 512, 1536, 512, 0, 0, 0, 0, 0, 0, 1.f);

        // Vt[b,h][d][k]
        transpose_v<<<dim3(256, 8), 256, 0, stream>>>(qkv, Vt);

        // scores = 0.125 * Q @ K^T   per (b,h):  [512,512]
        gemm_bt<0><<<dim3(8, 8, 256), 256, 0, stream>>>(
            qkv, qkv + 512, attnL, nullptr,
            1536, 1536, 512, 64,
            786432, 64, 786432, 64, 2097152, 262144, 0.125f);

        // in-place masked softmax, result stays in d_out (this IS output 1)
        softmax_kernel<<<32768, 256, 0, stream>>>(attnL, amask);

        // o = attn @ V  -> buf2 [16384,512] (token-major, cols h*64+d)
        gemm_bt<0><<<dim3(8, 1, 256), 256, 0, stream>>>(
            attnL, Vt, buf2, nullptr,
            512, 512, 512, 512,
            2097152, 262144, 262144, 32768, 262144, 64, 1.f);

        // proj = o @ Wout^T + b -> buf1 head (qkv dead now)
        gemm_bt<0><<<dim3(256, 8, 1), 256, 0, stream>>>(
            buf2, out_w + (long long)l * 262144, buf1, out_b + l * 512,
            512, 512, 512, 512, 0, 0, 0, 0, 0, 0, 1.f);

        // x = LN1(x + proj)
        add_ln<<<4096, 256, 0, stream>>>(x, buf1, ln1g + l * 512, ln1b + l * 512);

        // f = gelu(x @ W1^T + b1) -> buf1 [16384,2048]
        gemm_bt<1><<<dim3(256, 32, 1), 256, 0, stream>>>(
            x, f1w + (long long)l * 1048576, buf1, f1b + l * 2048,
            512, 512, 2048, 512, 0, 0, 0, 0, 0, 0, 1.f);

        // g = f @ W2^T + b2 -> buf2
        gemm_bt<0><<<dim3(256, 8, 1), 256, 0, stream>>>(
            buf1, f2w + (long long)l * 1048576, buf2, f2b + l * 512,
            2048, 2048, 512, 2048, 0, 0, 0, 0, 0, 0, 1.f);

        // x = LN2(x + g)
        add_ln<<<4096, 256, 0, stream>>>(x, buf2, ln2g + l * 512, ln2b + l * 512);
    }

    cls_head<<<64, 64, 0, stream>>>(x, clsw, clsb, outp);
}